// Round 5
// baseline (928.497 us; speedup 1.0000x reference)
//
#include <hip/hip_runtime.h>
#include <math.h>

#define N_TOT 32768
#define M_NBR 12
#define ORIG  92
#define EDGE  41
#define FD    128
#define HD    256
#define APC   256
#define NCRY  128

#define ESTR  48           // edge_frag row stride in bf16 (K padded 41->48)
#define WF_PER_LAYER 73728 // bf16 elems of swizzled conv weight frags per layer
#define WF_EMBED     12288
#define WF_H         32768

typedef __attribute__((ext_vector_type(8))) short bf16x8;
typedef __attribute__((ext_vector_type(4))) float f32x4;

__device__ __forceinline__ short f2bf(float f) {
    union { float f; unsigned u; } v; v.f = f;
    unsigned r = v.u + 0x7fffu + ((v.u >> 16) & 1u);   // RNE
    return (short)(r >> 16);
}
__device__ __forceinline__ float bf2f(short s) {
    union { unsigned u; float f; } v; v.u = ((unsigned)(unsigned short)s) << 16;
    return v.f;
}
__device__ __forceinline__ float softplus_f(float x) {
    return fmaxf(x, 0.0f) + __logf(1.0f + __expf(-fabsf(x)));
}
__device__ __forceinline__ float sigmoid_f(float x) {
    return 1.0f / (1.0f + __expf(-x));
}

// ---------------- weight pre-swizzle into B-fragment order ----------------
__global__ __launch_bounds__(256) void swizzle_kernel(
    const float* __restrict__ Wc_all, const float* __restrict__ Wn_all,
    const float* __restrict__ We_all, const float* __restrict__ Wg_all,
    const float* __restrict__ Wm_all, const float* __restrict__ W_embed,
    const float* __restrict__ W_h, short* __restrict__ dst_all)
{
    int gid = blockIdx.x * 256 + threadIdx.x;
    if (gid >= 33280) return;
    const float* W; short* dst; int K_real, fid, stride, l, nt, kt;
    if (gid < 27648) {
        int layer = gid / 9216;
        int rem = gid - layer * 9216;
        short* dbase = dst_all + layer * WF_PER_LAYER;
        if (rem < 2048)      { W = Wc_all + layer * 16384; dst = dbase;         K_real = 128; fid = rem; }
        else if (rem < 4096) { W = Wn_all + layer * 16384; dst = dbase + 16384; K_real = 128; fid = rem - 2048; }
        else if (rem < 5120) { W = We_all + layer * 5248;  dst = dbase + 32768; K_real = 41;  fid = rem - 4096; }
        else if (rem < 7168) { W = Wg_all + layer * 16384; dst = dbase + 40960; K_real = 128; fid = rem - 5120; }
        else                 { W = Wm_all + layer * 16384; dst = dbase + 57344; K_real = 128; fid = rem - 7168; }
        stride = 128; l = fid & 63; nt = (fid >> 6) & 7; kt = fid >> 9;
    } else if (gid < 29184) {
        fid = gid - 27648;
        W = W_embed; dst = dst_all + 3 * WF_PER_LAYER; K_real = ORIG; stride = 128;
        l = fid & 63; nt = (fid >> 6) & 7; kt = fid >> 9;
    } else {
        fid = gid - 29184;
        W = W_h; dst = dst_all + 3 * WF_PER_LAYER + WF_EMBED; K_real = 128; stride = 256;
        l = fid & 63; nt = (fid >> 6) & 15; kt = fid >> 10;
    }
    int n = nt * 16 + (l & 15), kb = kt * 32 + (l >> 4) * 8;
    bf16x8 v;
    #pragma unroll
    for (int j = 0; j < 8; ++j) {
        int k = kb + j;
        v[j] = (k < K_real) ? f2bf(W[k * stride + n]) : (short)0;
    }
    *(bf16x8*)(dst + fid * 8) = v;
}

// ---------------- edge prepass: nbr_fea fp32 [R,41] -> bf16 [R,48] ----------------
__global__ __launch_bounds__(256) void edge_prep_kernel(
    const float* __restrict__ nbr_fea, short* __restrict__ edge_frag)
{
    const long R = (long)N_TOT * M_NBR;
    const long gid = (long)blockIdx.x * 256 + threadIdx.x;   // one per 8 outputs
    const long row = gid / 6;
    const int c = (int)(gid - row * 6);
    if (row >= R) return;
    const float* src = nbr_fea + row * EDGE + c * 8;
    bf16x8 v;
    #pragma unroll
    for (int j = 0; j < 8; ++j)
        v[j] = (c * 8 + j < EDGE) ? f2bf(src[j]) : (short)0;
    *(bf16x8*)(edge_frag + row * ESTR + c * 8) = v;
}

// ---------------- embed MFMA: 64 atoms/block, 4 waves ----------------
__global__ __launch_bounds__(256) void embed_mfma_kernel(
    const float* __restrict__ atom_fea, const short* __restrict__ wef,
    const float* __restrict__ b, float* __restrict__ x, short* __restrict__ xbf)
{
    const int tid = threadIdx.x;
    const int w = tid >> 6, lane = tid & 63;
    const int q = lane >> 4, m = lane & 15;
    const int a0 = blockIdx.x * 64;
    const int arow = a0 + w * 16 + m;

    bf16x8 aA[3];
    const float* ap = atom_fea + (long)arow * ORIG;
    #pragma unroll
    for (int kt = 0; kt < 3; ++kt) {
        const int kb = kt * 32 + q * 8;
        bf16x8 v;
        if (kb + 7 < ORIG) {
            const float4 u0 = *(const float4*)(ap + kb);
            const float4 u1 = *(const float4*)(ap + kb + 4);
            v[0]=f2bf(u0.x); v[1]=f2bf(u0.y); v[2]=f2bf(u0.z); v[3]=f2bf(u0.w);
            v[4]=f2bf(u1.x); v[5]=f2bf(u1.y); v[6]=f2bf(u1.z); v[7]=f2bf(u1.w);
        } else {
            #pragma unroll
            for (int j = 0; j < 8; ++j) {
                const int k = kb + j;
                v[j] = (k < ORIG) ? f2bf(ap[k]) : (short)0;
            }
        }
        aA[kt] = v;
    }

    #pragma unroll
    for (int nt = 0; nt < 8; ++nt) {
        f32x4 C = {0.f, 0.f, 0.f, 0.f};
        #pragma unroll
        for (int kt = 0; kt < 3; ++kt)
            C = __builtin_amdgcn_mfma_f32_16x16x32_bf16(
                    aA[kt], *(const bf16x8*)(wef + ((kt * 8 + nt) * 64 + lane) * 8), C, 0, 0, 0);
        const int col = nt * 16 + m;
        const float bv = b[col];
        #pragma unroll
        for (int r = 0; r < 4; ++r) {
            const long n = a0 + w * 16 + q * 4 + r;
            const float val = C[r] + bv;
            x[n * FD + col] = val;
            xbf[n * FD + col] = f2bf(val);
        }
    }
}

// ---------------- fused MFMA conv layer: 16 atoms / block, 4 waves, 1 barrier ----
// inter_s: stride 128 bf16, 16B chunks XOR-swizzled by (row & 15).
// NOTE: no min-waves in launch_bounds — forcing 3 waves/EU caused catastrophic
// scratch spills in R4 (VGPR 128->84, WRITE_SIZE 25->211 MB/layer).
__global__ __launch_bounds__(256) void conv_mfma_kernel(
    const float* __restrict__ x_in, const short* __restrict__ xbf_in,
    float* __restrict__ x_out, short* __restrict__ xbf_out,
    const short* __restrict__ edge_frag, const int* __restrict__ nbr_idx,
    const short* __restrict__ wf,
    const float* __restrict__ bc, const float* __restrict__ bn,
    const float* __restrict__ be, const float* __restrict__ bg,
    const float* __restrict__ bm,
    const float* __restrict__ lns, const float* __restrict__ lnb)
{
    __shared__ short inter_s[192 * 128];   // 49152 B, swizzled
    __shared__ short phic_s[16 * 136];     // 4352 B, bf16

    const int tid = threadIdx.x;
    const int w = tid >> 6, lane = tid & 63;
    const int q = lane >> 4, m = lane & 15;
    const int a0 = blockIdx.x * 16;
    const long r0 = (long)a0 * M_NBR;

    const short* Wc = wf;
    const short* Wn = wf + 16384;
    const short* We = wf + 32768;
    const short* Wg = wf + 40960;
    const short* Wm = wf + 57344;

    // ---- early global loads: idx, edge frags, neighbor gathers ----
    int idx[3];
    #pragma unroll
    for (int i = 0; i < 3; ++i)
        idx[i] = nbr_idx[r0 + (w * 3 + i) * 16 + m];

    bf16x8 aE[3][2];
    #pragma unroll
    for (int i = 0; i < 3; ++i) {
        const long erow = r0 + (w * 3 + i) * 16 + m;
        aE[i][0] = *(const bf16x8*)(edge_frag + erow * ESTR + q * 8);
        if (q < 2) {
            aE[i][1] = *(const bf16x8*)(edge_frag + erow * ESTR + 32 + q * 8);
        } else {
            bf16x8 z;
            #pragma unroll
            for (int j = 0; j < 8; ++j) z[j] = 0;
            aE[i][1] = z;
        }
    }

    bf16x8 aN[3][4];
    #pragma unroll
    for (int i = 0; i < 3; ++i) {
        const long g = (long)idx[i] << 7;
        #pragma unroll
        for (int kt = 0; kt < 4; ++kt)
            aN[i][kt] = *(const bf16x8*)(xbf_in + g + kt * 32 + q * 8);
    }

    // ---- phi_c (wave w computes col-tiles nt=2w, 2w+1), bf16 into LDS ----
    {
        bf16x8 aC[4];
        #pragma unroll
        for (int kt = 0; kt < 4; ++kt)
            aC[kt] = *(const bf16x8*)(xbf_in + ((long)(a0 + m) << 7) + kt * 32 + q * 8);
        #pragma unroll
        for (int ii = 0; ii < 2; ++ii) {
            const int nt = w * 2 + ii;
            f32x4 C = {0.f, 0.f, 0.f, 0.f};
            #pragma unroll
            for (int kt = 0; kt < 4; ++kt)
                C = __builtin_amdgcn_mfma_f32_16x16x32_bf16(
                        aC[kt], *(const bf16x8*)(Wc + ((kt * 8 + nt) * 64 + lane) * 8), C, 0, 0, 0);
            const int col = nt * 16 + m;
            const float bcv = bc[col];
            #pragma unroll
            for (int r = 0; r < 4; ++r)
                phic_s[(q * 4 + r) * 136 + col] = f2bf(C[r] + bcv);
        }
    }
    __syncthreads();   // phic_s visible to all waves (only barrier)

    // ---- phi_n & phi_e GEMMs -> inter (bf16, swizzled LDS) ----
    #pragma unroll
    for (int nt = 0; nt < 8; ++nt) {
        f32x4 Cn[3], Ce[3];
        #pragma unroll
        for (int i = 0; i < 3; ++i) { Cn[i] = (f32x4){0.f,0.f,0.f,0.f}; Ce[i] = (f32x4){0.f,0.f,0.f,0.f}; }
        #pragma unroll
        for (int kt = 0; kt < 4; ++kt) {
            const bf16x8 bfr = *(const bf16x8*)(Wn + ((kt * 8 + nt) * 64 + lane) * 8);
            #pragma unroll
            for (int i = 0; i < 3; ++i)
                Cn[i] = __builtin_amdgcn_mfma_f32_16x16x32_bf16(aN[i][kt], bfr, Cn[i], 0, 0, 0);
        }
        #pragma unroll
        for (int kt = 0; kt < 2; ++kt) {
            const bf16x8 efr = *(const bf16x8*)(We + ((kt * 8 + nt) * 64 + lane) * 8);
            #pragma unroll
            for (int i = 0; i < 3; ++i)
                Ce[i] = __builtin_amdgcn_mfma_f32_16x16x32_bf16(aE[i][kt], efr, Ce[i], 0, 0, 0);
        }
        const int col = nt * 16 + m;
        const int chunkL = col >> 3, sub = col & 7;
        const float bnv = bn[col], bev = be[col];
        #pragma unroll
        for (int i = 0; i < 3; ++i) {
            const int rb = (w * 3 + i) * 16 + q * 4;
            #pragma unroll
            for (int r = 0; r < 4; ++r) {
                const int row = rb + r;
                const int atom = row / 12;
                const float pc = bf2f(phic_s[(atom & 15) * 136 + col]);
                const float iv = pc * (Cn[i][r] + bnv) * (Ce[i][r] + bev);
                inter_s[row * 128 + ((chunkL ^ (row & 15)) << 3) + sub] = f2bf(iv);
            }
        }
    }

    // ---- inter A-fragments (wave-private rows; in-wave lgkm ordering suffices) ----
    bf16x8 aI[3][4];
    #pragma unroll
    for (int i = 0; i < 3; ++i) {
        const int row = (w * 3 + i) * 16 + m;   // row & 15 == m
        #pragma unroll
        for (int kt = 0; kt < 4; ++kt)
            aI[i][kt] = *(const bf16x8*)(inter_s + row * 128 + (((kt * 4 + q) ^ m) << 3));
    }

    // ---- gate & mag GEMMs -> p = sigmoid(gate) * softplus(mag) (overwrite LDS) ----
    #pragma unroll
    for (int nt = 0; nt < 8; ++nt) {
        f32x4 Cg[3], Cm[3];
        #pragma unroll
        for (int i = 0; i < 3; ++i) { Cg[i] = (f32x4){0.f,0.f,0.f,0.f}; Cm[i] = (f32x4){0.f,0.f,0.f,0.f}; }
        #pragma unroll
        for (int kt = 0; kt < 4; ++kt) {
            const bf16x8 gfr = *(const bf16x8*)(Wg + ((kt * 8 + nt) * 64 + lane) * 8);
            const bf16x8 mfr = *(const bf16x8*)(Wm + ((kt * 8 + nt) * 64 + lane) * 8);
            #pragma unroll
            for (int i = 0; i < 3; ++i) {
                Cg[i] = __builtin_amdgcn_mfma_f32_16x16x32_bf16(aI[i][kt], gfr, Cg[i], 0, 0, 0);
                Cm[i] = __builtin_amdgcn_mfma_f32_16x16x32_bf16(aI[i][kt], mfr, Cm[i], 0, 0, 0);
            }
        }
        const int col = nt * 16 + m;
        const int chunkL = col >> 3, sub = col & 7;
        const float bgv = bg[col], bmv = bm[col];
        #pragma unroll
        for (int i = 0; i < 3; ++i) {
            const int rb = (w * 3 + i) * 16 + q * 4;
            #pragma unroll
            for (int r = 0; r < 4; ++r) {
                const int row = rb + r;
                const float g = sigmoid_f(Cg[i][r] + bgv);
                const float s = softplus_f(Cm[i][r] + bmv);
                inter_s[row * 128 + ((chunkL ^ (row & 15)) << 3) + sub] = f2bf(g * s);
            }
        }
    }
    // no barrier: thread (a*16+cg) is in wave a/4, which owns rows a*12..a*12+11

    // ---- neighbor-sum + LayerNorm + residual ----
    {
        const int a = tid >> 4;
        const int cg = tid & 15;
        float s8[8];
        #pragma unroll
        for (int j = 0; j < 8; ++j) s8[j] = 0.f;
        #pragma unroll
        for (int nb = 0; nb < 12; ++nb) {
            const int row = a * 12 + nb;
            const bf16x8 p = *(const bf16x8*)(inter_s + row * 128 + ((cg ^ (row & 15)) << 3));
            #pragma unroll
            for (int j = 0; j < 8; ++j) s8[j] += bf2f(p[j]);
        }
        float lsum = 0.f, lsq = 0.f;
        #pragma unroll
        for (int j = 0; j < 8; ++j) { lsum += s8[j]; lsq += s8[j] * s8[j]; }
        #pragma unroll
        for (int off = 1; off < 16; off <<= 1) {
            lsum += __shfl_xor(lsum, off, 64);
            lsq  += __shfl_xor(lsq,  off, 64);
        }
        const float mu = lsum * (1.0f / FD);
        float var = lsq * (1.0f / FD) - mu * mu;
        var = fmaxf(var, 0.0f);
        const float inv = rsqrtf(var + 1e-6f);
        const long xb = ((long)(a0 + a) << 7) + cg * 8;
        const float4 xr0 = *(const float4*)(x_in + xb);
        const float4 xr1 = *(const float4*)(x_in + xb + 4);
        const float xr[8] = {xr0.x, xr0.y, xr0.z, xr0.w, xr1.x, xr1.y, xr1.z, xr1.w};
        float o[8]; bf16x8 ob;
        #pragma unroll
        for (int j = 0; j < 8; ++j) {
            const int col = cg * 8 + j;
            const float y = (s8[j] - mu) * inv * lns[col] + lnb[col];
            const float v = xr[j] + y;
            o[j] = v; ob[j] = f2bf(v);
        }
        *(float4*)(x_out + xb)     = make_float4(o[0], o[1], o[2], o[3]);
        *(float4*)(x_out + xb + 4) = make_float4(o[4], o[5], o[6], o[7]);
        *(bf16x8*)(xbf_out + xb)   = ob;
    }
}

// ---------------- readout MFMA: 64 atoms/block, 4 waves ----------------
__global__ __launch_bounds__(256) void readout_mfma_kernel(
    const short* __restrict__ xbf, const short* __restrict__ whf,
    const float* __restrict__ bh, const float* __restrict__ Wo,
    const float* __restrict__ bo, float* __restrict__ out)
{
    const int tid = threadIdx.x;
    const int w = tid >> 6, lane = tid & 63;
    const int q = lane >> 4, m = lane & 15;
    const int a0 = blockIdx.x * 64;
    const int arow = a0 + w * 16 + m;

    bf16x8 aX[4];
    #pragma unroll
    for (int kt = 0; kt < 4; ++kt)
        aX[kt] = *(const bf16x8*)(xbf + ((long)arow << 7) + kt * 32 + q * 8);

    float e[4] = {0.f, 0.f, 0.f, 0.f};
    #pragma unroll
    for (int nt = 0; nt < 16; ++nt) {
        f32x4 C = {0.f, 0.f, 0.f, 0.f};
        #pragma unroll
        for (int kt = 0; kt < 4; ++kt)
            C = __builtin_amdgcn_mfma_f32_16x16x32_bf16(
                    aX[kt], *(const bf16x8*)(whf + ((kt * 16 + nt) * 64 + lane) * 8), C, 0, 0, 0);
        const int col = nt * 16 + m;
        const float bhv = bh[col], wov = Wo[col];
        #pragma unroll
        for (int r = 0; r < 4; ++r)
            e[r] += softplus_f(C[r] + bhv) * wov;
    }
    float esum = e[0] + e[1] + e[2] + e[3];
    #pragma unroll
    for (int off = 32; off > 0; off >>= 1)
        esum += __shfl_xor(esum, off, 64);
    if (lane == 0)
        atomicAdd(&out[a0 / APC], esum + 16.0f * bo[0]);
}

__global__ void zero_out_kernel(float* __restrict__ out) {
    if (threadIdx.x < NCRY) out[threadIdx.x] = 0.0f;
}

extern "C" void kernel_launch(void* const* d_in, const int* in_sizes, int n_in,
                              void* d_out, int out_size, void* d_ws, size_t ws_size,
                              hipStream_t stream) {
    const float* atom_fea = (const float*)d_in[0];
    const float* nbr_fea  = (const float*)d_in[1];
    const int*   nbr_idx  = (const int*)d_in[2];
    const float* W_embed  = (const float*)d_in[3];
    const float* b_embed  = (const float*)d_in[4];
    const float* W_center = (const float*)d_in[5];
    const float* b_center = (const float*)d_in[6];
    const float* W_nbr    = (const float*)d_in[7];
    const float* b_nbr    = (const float*)d_in[8];
    const float* W_edge   = (const float*)d_in[9];
    const float* b_edge   = (const float*)d_in[10];
    const float* W_gate   = (const float*)d_in[11];
    const float* b_gate   = (const float*)d_in[12];
    const float* W_mag    = (const float*)d_in[13];
    const float* b_mag    = (const float*)d_in[14];
    const float* ln_scale = (const float*)d_in[15];
    const float* ln_bias  = (const float*)d_in[16];
    const float* W_h      = (const float*)d_in[17];
    const float* b_h      = (const float*)d_in[18];
    const float* W_out    = (const float*)d_in[19];
    const float* b_out    = (const float*)d_in[20];

    float* out = (float*)d_out;
    const size_t NX = (size_t)N_TOT * FD;
    float* xA = (float*)d_ws;
    float* xB = xA + NX;
    short* xbfA = (short*)(xB + NX);
    short* xbfB = xbfA + NX;
    short* wfrag = xbfB + NX;                          // 266240 shorts
    short* edge_frag = wfrag + 266240;                 // 393216*48 shorts

    swizzle_kernel<<<130, 256, 0, stream>>>(W_center, W_nbr, W_edge, W_gate, W_mag,
                                            W_embed, W_h, wfrag);
    edge_prep_kernel<<<9216, 256, 0, stream>>>(nbr_fea, edge_frag);
    embed_mfma_kernel<<<N_TOT / 64, 256, 0, stream>>>(
        atom_fea, wfrag + 3 * WF_PER_LAYER, b_embed, xA, xbfA);

    const float* xi = xA; float* xo = xB;
    const short* xbi = xbfA; short* xbo = xbfB;
    for (int l = 0; l < 3; ++l) {
        conv_mfma_kernel<<<N_TOT / 16, 256, 0, stream>>>(
            xi, xbi, xo, xbo, edge_frag, nbr_idx,
            wfrag + (size_t)l * WF_PER_LAYER,
            b_center + (size_t)l * FD, b_nbr + (size_t)l * FD,
            b_edge + (size_t)l * FD, b_gate + (size_t)l * FD,
            b_mag + (size_t)l * FD,
            ln_scale + (size_t)l * FD, ln_bias + (size_t)l * FD);
        const float* tf = xo; xo = (float*)xi; xi = tf;
        const short* tb = xbo; xbo = (short*)xbi; xbi = tb;
    }

    zero_out_kernel<<<1, 128, 0, stream>>>(out);
    readout_mfma_kernel<<<N_TOT / 64, 256, 0, stream>>>(
        xbi, wfrag + 3 * WF_PER_LAYER + WF_EMBED, b_h, W_out, b_out, out);
}

// Round 6
// 478.702 us; speedup vs baseline: 1.9396x; 1.9396x over previous
//
#include <hip/hip_runtime.h>
#include <math.h>

#define N_TOT 32768
#define M_NBR 12
#define ORIG  92
#define EDGE  41
#define FD    128
#define HD    256
#define APC   256
#define NCRY  128

#define STR   136          // inter_s row stride in bf16
#define ESTR  48           // edge_frag row stride in bf16 (K padded 41->48)
#define WF_PER_LAYER 73728 // bf16 elems of swizzled conv weight frags per layer
#define WF_EMBED     12288
#define WF_H         32768

typedef __attribute__((ext_vector_type(8))) short bf16x8;
typedef __attribute__((ext_vector_type(4))) float f32x4;

__device__ __forceinline__ short f2bf(float f) {
    union { float f; unsigned u; } v; v.f = f;
    unsigned r = v.u + 0x7fffu + ((v.u >> 16) & 1u);   // RNE
    return (short)(r >> 16);
}
__device__ __forceinline__ float bf2f(short s) {
    union { unsigned u; float f; } v; v.u = ((unsigned)(unsigned short)s) << 16;
    return v.f;
}
__device__ __forceinline__ float softplus_f(float x) {
    return fmaxf(x, 0.0f) + __logf(1.0f + __expf(-fabsf(x)));
}
__device__ __forceinline__ float sigmoid_f(float x) {
    return 1.0f / (1.0f + __expf(-x));
}

// ---------------- weight pre-swizzle into B-fragment order ----------------
__global__ __launch_bounds__(256) void swizzle_kernel(
    const float* __restrict__ Wc_all, const float* __restrict__ Wn_all,
    const float* __restrict__ We_all, const float* __restrict__ Wg_all,
    const float* __restrict__ Wm_all, const float* __restrict__ W_embed,
    const float* __restrict__ W_h, short* __restrict__ dst_all)
{
    int gid = blockIdx.x * 256 + threadIdx.x;
    if (gid >= 33280) return;
    const float* W; short* dst; int K_real, fid, stride, l, nt, kt;
    if (gid < 27648) {
        int layer = gid / 9216;
        int rem = gid - layer * 9216;
        short* dbase = dst_all + layer * WF_PER_LAYER;
        if (rem < 2048)      { W = Wc_all + layer * 16384; dst = dbase;         K_real = 128; fid = rem; }
        else if (rem < 4096) { W = Wn_all + layer * 16384; dst = dbase + 16384; K_real = 128; fid = rem - 2048; }
        else if (rem < 5120) { W = We_all + layer * 5248;  dst = dbase + 32768; K_real = 41;  fid = rem - 4096; }
        else if (rem < 7168) { W = Wg_all + layer * 16384; dst = dbase + 40960; K_real = 128; fid = rem - 5120; }
        else                 { W = Wm_all + layer * 16384; dst = dbase + 57344; K_real = 128; fid = rem - 7168; }
        stride = 128; l = fid & 63; nt = (fid >> 6) & 7; kt = fid >> 9;
    } else if (gid < 29184) {
        fid = gid - 27648;
        W = W_embed; dst = dst_all + 3 * WF_PER_LAYER; K_real = ORIG; stride = 128;
        l = fid & 63; nt = (fid >> 6) & 7; kt = fid >> 9;
    } else {
        fid = gid - 29184;
        W = W_h; dst = dst_all + 3 * WF_PER_LAYER + WF_EMBED; K_real = 128; stride = 256;
        l = fid & 63; nt = (fid >> 6) & 15; kt = fid >> 10;
    }
    int n = nt * 16 + (l & 15), kb = kt * 32 + (l >> 4) * 8;
    bf16x8 v;
    #pragma unroll
    for (int j = 0; j < 8; ++j) {
        int k = kb + j;
        v[j] = (k < K_real) ? f2bf(W[k * stride + n]) : (short)0;
    }
    *(bf16x8*)(dst + fid * 8) = v;
}

// ---------------- edge prepass: nbr_fea fp32 [R,41] -> bf16 [R,48] ----------------
__global__ __launch_bounds__(256) void edge_prep_kernel(
    const float* __restrict__ nbr_fea, short* __restrict__ edge_frag)
{
    const long R = (long)N_TOT * M_NBR;
    const long gid = (long)blockIdx.x * 256 + threadIdx.x;   // one per 8 outputs
    const long row = gid / 6;
    const int c = (int)(gid - row * 6);
    if (row >= R) return;
    const float* src = nbr_fea + row * EDGE + c * 8;
    bf16x8 v;
    #pragma unroll
    for (int j = 0; j < 8; ++j)
        v[j] = (c * 8 + j < EDGE) ? f2bf(src[j]) : (short)0;
    *(bf16x8*)(edge_frag + row * ESTR + c * 8) = v;
}

// ---------------- embed MFMA: 64 atoms/block, 4 waves ----------------
__global__ __launch_bounds__(256) void embed_mfma_kernel(
    const float* __restrict__ atom_fea, const short* __restrict__ wef,
    const float* __restrict__ b, float* __restrict__ x, short* __restrict__ xbf)
{
    const int tid = threadIdx.x;
    const int w = tid >> 6, lane = tid & 63;
    const int q = lane >> 4, m = lane & 15;
    const int a0 = blockIdx.x * 64;
    const int arow = a0 + w * 16 + m;

    bf16x8 aA[3];
    const float* ap = atom_fea + (long)arow * ORIG;
    #pragma unroll
    for (int kt = 0; kt < 3; ++kt) {
        const int kb = kt * 32 + q * 8;
        bf16x8 v;
        if (kb + 7 < ORIG) {
            const float4 u0 = *(const float4*)(ap + kb);
            const float4 u1 = *(const float4*)(ap + kb + 4);
            v[0]=f2bf(u0.x); v[1]=f2bf(u0.y); v[2]=f2bf(u0.z); v[3]=f2bf(u0.w);
            v[4]=f2bf(u1.x); v[5]=f2bf(u1.y); v[6]=f2bf(u1.z); v[7]=f2bf(u1.w);
        } else {
            #pragma unroll
            for (int j = 0; j < 8; ++j) {
                const int k = kb + j;
                v[j] = (k < ORIG) ? f2bf(ap[k]) : (short)0;
            }
        }
        aA[kt] = v;
    }

    #pragma unroll
    for (int nt = 0; nt < 8; ++nt) {
        f32x4 C = {0.f, 0.f, 0.f, 0.f};
        #pragma unroll
        for (int kt = 0; kt < 3; ++kt)
            C = __builtin_amdgcn_mfma_f32_16x16x32_bf16(
                    aA[kt], *(const bf16x8*)(wef + ((kt * 8 + nt) * 64 + lane) * 8), C, 0, 0, 0);
        const int col = nt * 16 + m;
        const float bv = b[col];
        #pragma unroll
        for (int r = 0; r < 4; ++r) {
            const long n = a0 + w * 16 + q * 4 + r;
            const float val = C[r] + bv;
            x[n * FD + col] = val;
            xbf[n * FD + col] = f2bf(val);
        }
    }
}

// ---------------- fused MFMA conv layer: 16 atoms / block, 4 waves ----------------
// R3 structure exactly (186 us/layer measured) with one change: edge A-frags
// load from the bf16 edge_frag prepass instead of fp32 repack in-kernel.
// NOTE: plain __launch_bounds__(256) — min-waves pin caused spills (R4);
// early-issued fragment loads + bf16 phic caused residency collapse (R5).
__global__ __launch_bounds__(256) void conv_mfma_kernel(
    const float* __restrict__ x_in, const short* __restrict__ xbf_in,
    float* __restrict__ x_out, short* __restrict__ xbf_out,
    const short* __restrict__ edge_frag, const int* __restrict__ nbr_idx,
    const short* __restrict__ wf,
    const float* __restrict__ bc, const float* __restrict__ bn,
    const float* __restrict__ be, const float* __restrict__ bg,
    const float* __restrict__ bm,
    const float* __restrict__ lns, const float* __restrict__ lnb)
{
    __shared__ short inter_s[192 * STR];
    __shared__ float phic_s[16 * 132];
    __shared__ int   idx_s[192];

    const int tid = threadIdx.x;
    const int w = tid >> 6, lane = tid & 63;
    const int q = lane >> 4, m = lane & 15;
    const int a0 = blockIdx.x * 16;
    const long r0 = (long)a0 * M_NBR;

    const short* Wc = wf;
    const short* Wn = wf + 16384;
    const short* We = wf + 32768;
    const short* Wg = wf + 40960;
    const short* Wm = wf + 57344;

    if (tid < 192) idx_s[tid] = nbr_idx[r0 + tid];

    {
        bf16x8 aC[4];
        #pragma unroll
        for (int kt = 0; kt < 4; ++kt)
            aC[kt] = *(const bf16x8*)(xbf_in + ((long)(a0 + m) << 7) + kt * 32 + q * 8);
        #pragma unroll
        for (int ii = 0; ii < 2; ++ii) {
            const int nt = w * 2 + ii;
            f32x4 C = {0.f, 0.f, 0.f, 0.f};
            #pragma unroll
            for (int kt = 0; kt < 4; ++kt)
                C = __builtin_amdgcn_mfma_f32_16x16x32_bf16(
                        aC[kt], *(const bf16x8*)(Wc + ((kt * 8 + nt) * 64 + lane) * 8), C, 0, 0, 0);
            const int col = nt * 16 + m;
            const float bcv = bc[col];
            #pragma unroll
            for (int r = 0; r < 4; ++r)
                phic_s[(q * 4 + r) * 132 + col] = C[r] + bcv;
        }
    }
    __syncthreads();

    bf16x8 aN[3][4];
    #pragma unroll
    for (int i = 0; i < 3; ++i) {
        const int row = (w * 3 + i) * 16 + m;
        const long g = (long)idx_s[row] << 7;
        #pragma unroll
        for (int kt = 0; kt < 4; ++kt)
            aN[i][kt] = *(const bf16x8*)(xbf_in + g + kt * 32 + q * 8);
    }
    bf16x8 aE[3][2];
    #pragma unroll
    for (int i = 0; i < 3; ++i) {
        const long erow = r0 + (w * 3 + i) * 16 + m;
        aE[i][0] = *(const bf16x8*)(edge_frag + erow * ESTR + q * 8);
        if (q < 2) {
            aE[i][1] = *(const bf16x8*)(edge_frag + erow * ESTR + 32 + q * 8);
        } else {
            bf16x8 z;
            #pragma unroll
            for (int j = 0; j < 8; ++j) z[j] = 0;
            aE[i][1] = z;
        }
    }

    #pragma unroll
    for (int nt = 0; nt < 8; ++nt) {
        f32x4 Cn[3], Ce[3];
        #pragma unroll
        for (int i = 0; i < 3; ++i) { Cn[i] = (f32x4){0.f,0.f,0.f,0.f}; Ce[i] = (f32x4){0.f,0.f,0.f,0.f}; }
        #pragma unroll
        for (int kt = 0; kt < 4; ++kt) {
            const bf16x8 bfr = *(const bf16x8*)(Wn + ((kt * 8 + nt) * 64 + lane) * 8);
            #pragma unroll
            for (int i = 0; i < 3; ++i)
                Cn[i] = __builtin_amdgcn_mfma_f32_16x16x32_bf16(aN[i][kt], bfr, Cn[i], 0, 0, 0);
        }
        #pragma unroll
        for (int kt = 0; kt < 2; ++kt) {
            const bf16x8 efr = *(const bf16x8*)(We + ((kt * 8 + nt) * 64 + lane) * 8);
            #pragma unroll
            for (int i = 0; i < 3; ++i)
                Ce[i] = __builtin_amdgcn_mfma_f32_16x16x32_bf16(aE[i][kt], efr, Ce[i], 0, 0, 0);
        }
        const int col = nt * 16 + m;
        const float bnv = bn[col], bev = be[col];
        #pragma unroll
        for (int i = 0; i < 3; ++i) {
            const int rb = (w * 3 + i) * 16 + q * 4;
            #pragma unroll
            for (int r = 0; r < 4; ++r) {
                const int row = rb + r;
                const int atom = row / 12;
                const float iv = phic_s[atom * 132 + col] * (Cn[i][r] + bnv) * (Ce[i][r] + bev);
                inter_s[row * STR + col] = f2bf(iv);
            }
        }
    }

    bf16x8 aI[3][4];
    #pragma unroll
    for (int i = 0; i < 3; ++i) {
        const int row = (w * 3 + i) * 16 + m;
        #pragma unroll
        for (int kt = 0; kt < 4; ++kt)
            aI[i][kt] = *(const bf16x8*)(inter_s + row * STR + kt * 32 + q * 8);
    }

    #pragma unroll
    for (int nt = 0; nt < 8; ++nt) {
        f32x4 Cg[3], Cm[3];
        #pragma unroll
        for (int i = 0; i < 3; ++i) { Cg[i] = (f32x4){0.f,0.f,0.f,0.f}; Cm[i] = (f32x4){0.f,0.f,0.f,0.f}; }
        #pragma unroll
        for (int kt = 0; kt < 4; ++kt) {
            const bf16x8 gfr = *(const bf16x8*)(Wg + ((kt * 8 + nt) * 64 + lane) * 8);
            const bf16x8 mfr = *(const bf16x8*)(Wm + ((kt * 8 + nt) * 64 + lane) * 8);
            #pragma unroll
            for (int i = 0; i < 3; ++i) {
                Cg[i] = __builtin_amdgcn_mfma_f32_16x16x32_bf16(aI[i][kt], gfr, Cg[i], 0, 0, 0);
                Cm[i] = __builtin_amdgcn_mfma_f32_16x16x32_bf16(aI[i][kt], mfr, Cm[i], 0, 0, 0);
            }
        }
        const int col = nt * 16 + m;
        const float bgv = bg[col], bmv = bm[col];
        #pragma unroll
        for (int i = 0; i < 3; ++i) {
            const int rb = (w * 3 + i) * 16 + q * 4;
            #pragma unroll
            for (int r = 0; r < 4; ++r) {
                const float g = sigmoid_f(Cg[i][r] + bgv);
                const float s = softplus_f(Cm[i][r] + bmv);
                inter_s[(rb + r) * STR + col] = f2bf(g * s);
            }
        }
    }
    __syncthreads();

    {
        const int a = tid >> 4;
        const int cg = tid & 15;
        float s8[8];
        #pragma unroll
        for (int j = 0; j < 8; ++j) s8[j] = 0.f;
        #pragma unroll
        for (int nb = 0; nb < 12; ++nb) {
            const bf16x8 p = *(const bf16x8*)(inter_s + (a * 12 + nb) * STR + cg * 8);
            #pragma unroll
            for (int j = 0; j < 8; ++j) s8[j] += bf2f(p[j]);
        }
        float lsum = 0.f, lsq = 0.f;
        #pragma unroll
        for (int j = 0; j < 8; ++j) { lsum += s8[j]; lsq += s8[j] * s8[j]; }
        #pragma unroll
        for (int off = 1; off < 16; off <<= 1) {
            lsum += __shfl_xor(lsum, off, 64);
            lsq  += __shfl_xor(lsq,  off, 64);
        }
        const float mu = lsum * (1.0f / FD);
        float var = lsq * (1.0f / FD) - mu * mu;
        var = fmaxf(var, 0.0f);
        const float inv = rsqrtf(var + 1e-6f);
        const long xb = ((long)(a0 + a) << 7) + cg * 8;
        const float4 xr0 = *(const float4*)(x_in + xb);
        const float4 xr1 = *(const float4*)(x_in + xb + 4);
        const float xr[8] = {xr0.x, xr0.y, xr0.z, xr0.w, xr1.x, xr1.y, xr1.z, xr1.w};
        float o[8]; bf16x8 ob;
        #pragma unroll
        for (int j = 0; j < 8; ++j) {
            const int col = cg * 8 + j;
            const float y = (s8[j] - mu) * inv * lns[col] + lnb[col];
            const float v = xr[j] + y;
            o[j] = v; ob[j] = f2bf(v);
        }
        *(float4*)(x_out + xb)     = make_float4(o[0], o[1], o[2], o[3]);
        *(float4*)(x_out + xb + 4) = make_float4(o[4], o[5], o[6], o[7]);
        *(bf16x8*)(xbf_out + xb)   = ob;
    }
}

// ---------------- readout MFMA: 64 atoms/block, 4 waves ----------------
__global__ __launch_bounds__(256) void readout_mfma_kernel(
    const short* __restrict__ xbf, const short* __restrict__ whf,
    const float* __restrict__ bh, const float* __restrict__ Wo,
    const float* __restrict__ bo, float* __restrict__ out)
{
    const int tid = threadIdx.x;
    const int w = tid >> 6, lane = tid & 63;
    const int q = lane >> 4, m = lane & 15;
    const int a0 = blockIdx.x * 64;
    const int arow = a0 + w * 16 + m;

    bf16x8 aX[4];
    #pragma unroll
    for (int kt = 0; kt < 4; ++kt)
        aX[kt] = *(const bf16x8*)(xbf + ((long)arow << 7) + kt * 32 + q * 8);

    float e[4] = {0.f, 0.f, 0.f, 0.f};
    #pragma unroll
    for (int nt = 0; nt < 16; ++nt) {
        f32x4 C = {0.f, 0.f, 0.f, 0.f};
        #pragma unroll
        for (int kt = 0; kt < 4; ++kt)
            C = __builtin_amdgcn_mfma_f32_16x16x32_bf16(
                    aX[kt], *(const bf16x8*)(whf + ((kt * 16 + nt) * 64 + lane) * 8), C, 0, 0, 0);
        const int col = nt * 16 + m;
        const float bhv = bh[col], wov = Wo[col];
        #pragma unroll
        for (int r = 0; r < 4; ++r)
            e[r] += softplus_f(C[r] + bhv) * wov;
    }
    float esum = e[0] + e[1] + e[2] + e[3];
    #pragma unroll
    for (int off = 32; off > 0; off >>= 1)
        esum += __shfl_xor(esum, off, 64);
    if (lane == 0)
        atomicAdd(&out[a0 / APC], esum + 16.0f * bo[0]);
}

__global__ void zero_out_kernel(float* __restrict__ out) {
    if (threadIdx.x < NCRY) out[threadIdx.x] = 0.0f;
}

extern "C" void kernel_launch(void* const* d_in, const int* in_sizes, int n_in,
                              void* d_out, int out_size, void* d_ws, size_t ws_size,
                              hipStream_t stream) {
    const float* atom_fea = (const float*)d_in[0];
    const float* nbr_fea  = (const float*)d_in[1];
    const int*   nbr_idx  = (const int*)d_in[2];
    const float* W_embed  = (const float*)d_in[3];
    const float* b_embed  = (const float*)d_in[4];
    const float* W_center = (const float*)d_in[5];
    const float* b_center = (const float*)d_in[6];
    const float* W_nbr    = (const float*)d_in[7];
    const float* b_nbr    = (const float*)d_in[8];
    const float* W_edge   = (const float*)d_in[9];
    const float* b_edge   = (const float*)d_in[10];
    const float* W_gate   = (const float*)d_in[11];
    const float* b_gate   = (const float*)d_in[12];
    const float* W_mag    = (const float*)d_in[13];
    const float* b_mag    = (const float*)d_in[14];
    const float* ln_scale = (const float*)d_in[15];
    const float* ln_bias  = (const float*)d_in[16];
    const float* W_h      = (const float*)d_in[17];
    const float* b_h      = (const float*)d_in[18];
    const float* W_out    = (const float*)d_in[19];
    const float* b_out    = (const float*)d_in[20];

    float* out = (float*)d_out;
    const size_t NX = (size_t)N_TOT * FD;
    float* xA = (float*)d_ws;
    float* xB = xA + NX;
    short* xbfA = (short*)(xB + NX);
    short* xbfB = xbfA + NX;
    short* wfrag = xbfB + NX;                          // 266240 shorts
    short* edge_frag = wfrag + 266240;                 // 393216*48 shorts

    swizzle_kernel<<<130, 256, 0, stream>>>(W_center, W_nbr, W_edge, W_gate, W_mag,
                                            W_embed, W_h, wfrag);
    edge_prep_kernel<<<9216, 256, 0, stream>>>(nbr_fea, edge_frag);
    embed_mfma_kernel<<<N_TOT / 64, 256, 0, stream>>>(
        atom_fea, wfrag + 3 * WF_PER_LAYER, b_embed, xA, xbfA);

    const float* xi = xA; float* xo = xB;
    const short* xbi = xbfA; short* xbo = xbfB;
    for (int l = 0; l < 3; ++l) {
        conv_mfma_kernel<<<N_TOT / 16, 256, 0, stream>>>(
            xi, xbi, xo, xbo, edge_frag, nbr_idx,
            wfrag + (size_t)l * WF_PER_LAYER,
            b_center + (size_t)l * FD, b_nbr + (size_t)l * FD,
            b_edge + (size_t)l * FD, b_gate + (size_t)l * FD,
            b_mag + (size_t)l * FD,
            ln_scale + (size_t)l * FD, ln_bias + (size_t)l * FD);
        const float* tf = xo; xo = (float*)xi; xi = tf;
        const short* tb = xbo; xbo = (short*)xbi; xbi = tb;
    }

    zero_out_kernel<<<1, 128, 0, stream>>>(out);
    readout_mfma_kernel<<<N_TOT / 64, 256, 0, stream>>>(
        xbi, wfrag + 3 * WF_PER_LAYER + WF_EMBED, b_h, W_out, b_out, out);
}